// Round 1
// 569.997 us; speedup vs baseline: 1.0538x; 1.0538x over previous
//
#include <hip/hip_runtime.h>
#include <math.h>

// ---------------- problem constants ----------------
#define B_DIM   4
#define S_DIM   4096
#define D_DIM   2048
#define DFF_DIM 8192
#define K_TOP   512
#define M_ROWS  (B_DIM * K_TOP)   // 2048 selected rows total
#define NSPLIT  4                 // split-K factor for gemm2

typedef _Float16 half8 __attribute__((ext_vector_type(8)));
typedef _Float16 half4 __attribute__((ext_vector_type(4)));
typedef float    floatx4 __attribute__((ext_vector_type(4)));

// ---------------- workspace layout (bytes) ----------------
// logits [B*S] f32 (64KB; selmap int32 OVERLAYS it - logits dead after topk key-load)
// tokens [B*k] i32 | rw [B*k] f32 | fx [2048][2048] f16
// W1T [8192][2048] f16 | W2T [2048][8192] f16 | h [2048][8192] f16
// partials (gemm2 split-K, f16 [4][2048][2048] = 32 MiB) overlay W1T (dead after gemm1).
static const size_t OFF_LOGITS = 0;
static const size_t OFF_SELMAP = 0;        // overlay (see topk_select)
static const size_t OFF_TOK    = 65536;
static const size_t OFF_RW     = 73728;
static const size_t OFF_FX     = 81920;
static const size_t OFF_W1T    = OFF_FX  + (size_t)M_ROWS * D_DIM * 2;      //  +8 MiB
static const size_t OFF_W2T    = OFF_W1T + (size_t)DFF_DIM * D_DIM * 2;     // +32 MiB
static const size_t OFF_H      = OFF_W2T + (size_t)D_DIM * DFF_DIM * 2;     // +32 MiB
static const size_t WS_NEEDED  = OFF_H   + (size_t)M_ROWS * DFF_DIM * 2;    // +32 MiB  (~104 MiB)
static const size_t OFF_PART   = OFF_W1T;  // overlay

// ---------------- helpers ----------------
__device__ __forceinline__ void async_ld16(const void* g, void* l) {
  // 16B direct global->LDS; LDS dest = wave-uniform base + lane*16
  __builtin_amdgcn_global_load_lds((const __attribute__((address_space(1))) unsigned int*)g,
                                   (__attribute__((address_space(3))) unsigned int*)l,
                                   16, 0, 0);
}

// gfx9 waitcnt imm: vm[3:0]+[15:14], exp[6:4], lgkm[11:8]
#define WAITCNT_VM0   0x0F70   // vmcnt(0), exp/lgkm ignored
#define WAITCNT_LGKM0 0xC07F   // lgkmcnt(0), vm/exp ignored

// ---------------- router logits: one wave per token row ----------------
__global__ __launch_bounds__(256) void router_logits(const float* __restrict__ x,
                                                     const float* __restrict__ Wr,
                                                     const float* __restrict__ br,
                                                     float* __restrict__ logits) {
  int row  = blockIdx.x * 4 + (threadIdx.x >> 6);
  int lane = threadIdx.x & 63;
  const float4* xr = (const float4*)(x + (size_t)row * D_DIM);
  const float4* wr = (const float4*)Wr;
  float s = 0.f;
#pragma unroll
  for (int i = 0; i < (D_DIM / 4) / 64; ++i) {     // 8 float4 per lane
    float4 a = xr[lane + i * 64];
    float4 w = wr[lane + i * 64];
    s += a.x * w.x + a.y * w.y + a.z * w.z + a.w * w.w;
  }
#pragma unroll
  for (int off = 32; off > 0; off >>= 1) s += __shfl_down(s, off, 64);
  if (lane == 0) logits[row] = s + br[0];
}

// ---------------- top-k (one block per batch) ----------------
// MSB radix select with parallel suffix-scan bin selection, single-scan ordered
// compaction. Also writes selmap[b*S+s] = selected-slot-or--1 (OVERLAYS logits:
// per-thread aliasing is safe - thread t only ever touches s == t (mod 256)).
__global__ __launch_bounds__(256) void topk_select(const float* logits,
                                                   int* selmap,
                                                   int* __restrict__ tokens,
                                                   float* __restrict__ rw) {
  int b = blockIdx.x;
  const float* lg = logits + (size_t)b * S_DIM;
  __shared__ unsigned int keys[S_DIM];
  __shared__ unsigned int bins[256];
  __shared__ unsigned int sscan[256];
  __shared__ unsigned int sh_prefix, sh_r;
  __shared__ float sel_logit[K_TOP];
  __shared__ float red[8];

  int tid = threadIdx.x;
  for (int s = tid; s < S_DIM; s += 256) {
    unsigned int u = __float_as_uint(lg[s]);
    keys[s] = (u & 0x80000000u) ? ~u : (u | 0x80000000u);   // order-preserving key
    selmap[b * S_DIM + s] = -1;   // aliases lg[s]: same thread, read-then-write
  }
  if (tid == 0) { sh_prefix = 0u; sh_r = K_TOP; }
  __syncthreads();

  // 4 radix passes: exact key of the K_TOP-th largest (duplicate-safe)
  for (int p = 24; p >= 0; p -= 8) {
    bins[tid] = 0u;
    __syncthreads();
    unsigned int prefix = sh_prefix;
    unsigned int maskhi = (p == 24) ? 0u : (0xFFFFFFFFu << (p + 8));
    for (int s = tid; s < S_DIM; s += 256) {
      unsigned int kk = keys[s];
      if ((kk & maskhi) == prefix) atomicAdd(&bins[(kk >> p) & 255u], 1u);
    }
    __syncthreads();
    sscan[tid] = bins[255 - tid];
    __syncthreads();
#pragma unroll
    for (int off = 1; off < 256; off <<= 1) {
      unsigned int v = (tid >= off) ? sscan[tid - off] : 0u;
      __syncthreads();
      sscan[tid] += v;
      __syncthreads();
    }
    unsigned int r = sh_r;
    unsigned int above = (tid > 0) ? sscan[tid - 1] : 0u;
    bool hit = (sscan[tid] >= r) && (above < r);   // exactly one thread
    __syncthreads();
    if (hit) {
      sh_prefix = prefix | ((unsigned int)(255 - tid) << p);
      sh_r = r - above;
    }
    __syncthreads();
  }
  unsigned int T = sh_prefix;

  // single-scan ordered compaction: thread owns indices [tid*16, tid*16+16)
  int s0 = tid * 16;
  unsigned int g = 0, e = 0;
#pragma unroll
  for (int j = 0; j < 16; ++j) {
    unsigned int kk = keys[s0 + j];
    g += (kk > T);
    e += (kk == T);
  }
  sscan[tid] = g | (e << 16);
  __syncthreads();
#pragma unroll
  for (int off = 1; off < 256; off <<= 1) {
    unsigned int v = (tid >= off) ? sscan[tid - off] : 0u;
    __syncthreads();
    sscan[tid] += v;
    __syncthreads();
  }
  unsigned int incl = sscan[tid];
  unsigned int Gtot = sscan[255] & 0xFFFFu;
  unsigned int need = (unsigned int)K_TOP - Gtot;      // ties: lowest index (matches lax.top_k)
  unsigned int gr = (incl & 0xFFFFu) - g;
  unsigned int er = (incl >> 16) - e;
#pragma unroll
  for (int j = 0; j < 16; ++j) {
    unsigned int kk = keys[s0 + j];
    if (kk > T) {
      unsigned int pos = gr + (er < need ? er : need);
      tokens[b * K_TOP + (int)pos] = s0 + j;
      sel_logit[pos] = __uint_as_float((kk & 0x80000000u) ? (kk & 0x7FFFFFFFu) : ~kk);
      selmap[b * S_DIM + s0 + j] = (int)pos;
      gr++;
    } else if (kk == T) {
      if (er < need) {
        unsigned int pos = gr + er;
        tokens[b * K_TOP + (int)pos] = s0 + j;
        sel_logit[pos] = __uint_as_float((kk & 0x80000000u) ? (kk & 0x7FFFFFFFu) : ~kk);
        selmap[b * S_DIM + s0 + j] = (int)pos;
      }
      er++;
    }
  }
  __syncthreads();

  // softmax over the selected logits
  int lane = tid & 63, wv = tid >> 6;
  float mx = -1e30f;
  for (int i = tid; i < K_TOP; i += 256) mx = fmaxf(mx, sel_logit[i]);
#pragma unroll
  for (int off = 32; off > 0; off >>= 1) mx = fmaxf(mx, __shfl_down(mx, off, 64));
  if (lane == 0) red[wv] = mx;
  __syncthreads();
  if (tid == 0) red[0] = fmaxf(fmaxf(red[0], red[1]), fmaxf(red[2], red[3]));
  __syncthreads();
  float M = red[0];
  float sm = 0.f;
  for (int i = tid; i < K_TOP; i += 256) sm += expf(sel_logit[i] - M);
#pragma unroll
  for (int off = 32; off > 0; off >>= 1) sm += __shfl_down(sm, off, 64);
  if (lane == 0) red[4 + wv] = sm;
  __syncthreads();
  if (tid == 0) red[4] = red[4] + red[5] + red[6] + red[7];
  __syncthreads();
  float SUM = red[4];
  for (int i = tid; i < K_TOP; i += 256) rw[b * K_TOP + i] = expf(sel_logit[i] - M) / SUM;
}

// ---------------- transpose + f32->f16 convert: in[K][N] -> out[N][K] ----------------
__global__ __launch_bounds__(256) void transpose_cvt(const float* __restrict__ in,
                                                     _Float16* __restrict__ out,
                                                     int K, int N) {
  __shared__ float tile[64][65];
  int nb = blockIdx.x * 64, kb = blockIdx.y * 64;
  int tid = threadIdx.x;
  int lr = tid >> 4;            // 0..15
  int lc = (tid & 15) * 4;      // col offset
#pragma unroll
  for (int p = 0; p < 4; ++p) {
    int row = p * 16 + lr;
    float4 v = *(const float4*)(in + (size_t)(kb + row) * N + nb + lc);
    tile[row][lc] = v.x; tile[row][lc + 1] = v.y; tile[row][lc + 2] = v.z; tile[row][lc + 3] = v.w;
  }
  __syncthreads();
#pragma unroll
  for (int p = 0; p < 2; ++p) {
    int cc = p * 256 + tid;
    int n  = cc >> 3;           // 0..63
    int kc = (cc & 7) * 8;
    half8 o;
#pragma unroll
    for (int j = 0; j < 8; ++j) o[j] = (_Float16)tile[kc + j][n];
    *(half8*)(out + (size_t)(nb + n) * K + kb + kc) = o;
  }
}

// ---------------- gather selected rows of x -> f16 fx [M_ROWS][D] ----------------
__global__ __launch_bounds__(256) void gather_cvt(const float* __restrict__ x,
                                                  const int* __restrict__ tokens,
                                                  _Float16* __restrict__ fx) {
  int row = blockIdx.x;            // 0..2047
  int b = row >> 9;
  int token = tokens[row];
  const float4* src = (const float4*)(x + ((size_t)b * S_DIM + token) * D_DIM);
  half4* dst = (half4*)(fx + (size_t)row * D_DIM);
  for (int i = threadIdx.x; i < D_DIM / 4; i += 256) {
    float4 v = src[i];
    half4 o;
    o[0] = (_Float16)v.x; o[1] = (_Float16)v.y; o[2] = (_Float16)v.z; o[3] = (_Float16)v.w;
    dst[i] = o;
  }
}

// ---------------- f16 GEMM, C = A @ Bt^T ------------------------------------------
// 256x256 tile, BK=64, 512 thr = 8 waves (2M x 4N), per-wave 128x64, 128 KiB LDS.
// Deep-pipelined 4-phase schedule (m201-style): all 8 global_load_lds for tile t+1
// issue at phase 1 of tile t; single vmcnt(0) drain at end of phase 4 has 3 phases
// (~1500 cyc) of lead, so loads stay in flight across 6 barriers. LDS is XOR-chunk
// swizzled (chunk ^= row&7, 16B granularity): linear global_load_lds dest + inverse-
// swizzled per-lane GLOBAL source + swizzled ds_read (both-sides rule). 2-way bank
// aliasing only (free). setprio(1) wraps each 16-MFMA cluster.
// EPI 0: Co = f16(gelu(C + bias))   EPI 2: f16 split-K partial (bias deferred)
template <int EPI>
__global__ __launch_bounds__(512, 2) void gemm256(const _Float16* __restrict__ A,
                                                  const _Float16* __restrict__ Bt,
                                                  const float* __restrict__ bias,
                                                  _Float16* __restrict__ Co,
                                                  int M, int N, int K, int Kspan) {
  __shared__ _Float16 As[2][256 * 64];   // 64 KiB
  __shared__ _Float16 Bs[2][256 * 64];   // 64 KiB
  const int tid  = threadIdx.x;
  const int lane = tid & 63;
  const int wave = tid >> 6;     // 0..7
  const int wm   = wave >> 2;    // 0..1  (M strip of 128)
  const int wn   = wave & 3;     // 0..3  (N strip of 64)

  // XCD-aware block swizzle (nwg % 8 == 0 in every launch here -> bijective)
  const int nwg = gridDim.x * gridDim.y;
  const int bid = blockIdx.y * gridDim.x + blockIdx.x;
  const int swb = (bid & 7) * (nwg >> 3) + (bid >> 3);
  const int bn  = (swb % gridDim.x) * 256;
  const int bm  = (swb / gridDim.x) * 256;

  const int k0 = blockIdx.z * Kspan;
  const int nt = Kspan / 64;

  // ---- staging sources (per-lane, inverse-swizzled) ----
  // LDS unit h = rows [h*128, h*128+128) x 64 halves (16 KiB); wave handles chunks
  // {2w, 2w+1} of each unit (1 KiB per global_load_lds). For LDS row r, 16B slot s
  // holds logical k-chunk s ^ (r&7); here r&7 == lane>>3, s == lane&7.
  const int lr  = lane >> 3;                 // 0..7
  const int lcs = ((lane & 7) ^ lr) * 8;     // logical k-offset (halves) for this lane's slot
  const _Float16* sa[2][2];
  const _Float16* sb[2][2];
  int ldso[2][2];
#pragma unroll
  for (int h = 0; h < 2; ++h)
#pragma unroll
    for (int ci = 0; ci < 2; ++ci) {
      const int cip = 2 * wave + ci;                 // 0..15
      const int r   = h * 128 + cip * 8 + lr;        // 0..255
      sa[h][ci] = A  + (size_t)(bm + r) * K + k0 + lcs;
      sb[h][ci] = Bt + (size_t)(bn + r) * K + k0 + lcs;
      ldso[h][ci] = h * 8192 + cip * 512;            // halves
    }

  // ---- fragment read offsets (halves), swizzled ----
  const int mr   = lane & 15;
  const int ksub = lane >> 4;                 // 0..3
  const int xr   = mr & 7;                    // == row&7 for every frag row
  const int sc0  = (ksub ^ xr) * 8;           // kh=0 slot offset
  const int sc1  = ((ksub ^ xr) ^ 4) * 8;     // kh=1: (4+ksub)^xr == (ksub^xr)^4
  const int aro  = (wm * 128 + mr) * 64;
  const int bro  = (wn * 64 + mr) * 64;

  floatx4 acc[8][4] = {};

  // prologue: stage tile 0 -> buf 0
#pragma unroll
  for (int h = 0; h < 2; ++h)
#pragma unroll
    for (int ci = 0; ci < 2; ++ci) {
      async_ld16(sa[h][ci], &As[0][ldso[h][ci]]);
      async_ld16(sb[h][ci], &Bs[0][ldso[h][ci]]);
    }
  __builtin_amdgcn_s_waitcnt(WAITCNT_VM0);
  __builtin_amdgcn_s_barrier();

  for (int t = 0; t < nt; ++t) {
    const _Float16* as = As[t & 1];
    const _Float16* bs = Bs[t & 1];
    half8 af[4], bf[4];

    // ---- P1: (mhalf 0, khalf 0); burst-stage ALL of tile t+1 -> other buffer ----
#pragma unroll
    for (int i = 0; i < 4; ++i) af[i] = *(const half8*)(as + aro + i * 1024 + sc0);
#pragma unroll
    for (int j = 0; j < 4; ++j) bf[j] = *(const half8*)(bs + bro + j * 1024 + sc0);
    if (t + 1 < nt) {
      const int nb = (t + 1) & 1;
      const int kt = (t + 1) * 64;
#pragma unroll
      for (int h = 0; h < 2; ++h)
#pragma unroll
        for (int ci = 0; ci < 2; ++ci) {
          async_ld16(sa[h][ci] + kt, &As[nb][ldso[h][ci]]);
          async_ld16(sb[h][ci] + kt, &Bs[nb][ldso[h][ci]]);
        }
    }
    __builtin_amdgcn_s_barrier();
    __builtin_amdgcn_s_waitcnt(WAITCNT_LGKM0);
    __builtin_amdgcn_s_setprio(1);
#pragma unroll
    for (int i = 0; i < 4; ++i)
#pragma unroll
      for (int j = 0; j < 4; ++j)
        acc[i][j] = __builtin_amdgcn_mfma_f32_16x16x32_f16(af[i], bf[j], acc[i][j], 0, 0, 0);
    __builtin_amdgcn_s_setprio(0);
    __builtin_amdgcn_s_barrier();

    // ---- P2: (mhalf 1, khalf 0) — reuse bf(k0) ----
#pragma unroll
    for (int i = 0; i < 4; ++i) af[i] = *(const half8*)(as + aro + 4096 + i * 1024 + sc0);
    __builtin_amdgcn_s_barrier();
    __builtin_amdgcn_s_waitcnt(WAITCNT_LGKM0);
    __builtin_amdgcn_s_setprio(1);
#pragma unroll
    for (int i = 0; i < 4; ++i)
#pragma unroll
      for (int j = 0; j < 4; ++j)
        acc[4 + i][j] = __builtin_amdgcn_mfma_f32_16x16x32_f16(af[i], bf[j], acc[4 + i][j], 0, 0, 0);
    __builtin_amdgcn_s_setprio(0);
    __builtin_amdgcn_s_barrier();

    // ---- P3: (mhalf 0, khalf 1) ----
#pragma unroll
    for (int i = 0; i < 4; ++i) af[i] = *(const half8*)(as + aro + i * 1024 + sc1);
#pragma unroll
    for (int j = 0; j < 4; ++j) bf[j] = *(const half8*)(bs + bro + j * 1024 + sc1);
    __builtin_amdgcn_s_barrier();
    __builtin_amdgcn_s_waitcnt(WAITCNT_LGKM0);
    __builtin_amdgcn_s_setprio(1);
#pragma unroll
    for (int i = 0; i < 4; ++i)
#pragma unroll
      for (int j = 0; j < 4; ++j)
        acc[i][j] = __builtin_amdgcn_mfma_f32_16x16x32_f16(af[i], bf[j], acc[i][j], 0, 0, 0);
    __builtin_amdgcn_s_setprio(0);
    __builtin_amdgcn_s_barrier();

    // ---- P4: (mhalf 1, khalf 1); drain tile t+1 stages (issued 3 phases ago) ----
#pragma unroll
    for (int i = 0; i < 4; ++i) af[i] = *(const half8*)(as + aro + 4096 + i * 1024 + sc1);
    __builtin_amdgcn_s_barrier();
    __builtin_amdgcn_s_waitcnt(WAITCNT_LGKM0);
    __builtin_amdgcn_s_setprio(1);
#pragma unroll
    for (int i = 0; i < 4; ++i)
#pragma unroll
      for (int j = 0; j < 4; ++j)
        acc[4 + i][j] = __builtin_amdgcn_mfma_f32_16x16x32_f16(af[i], bf[j], acc[4 + i][j], 0, 0, 0);
    __builtin_amdgcn_s_setprio(0);
    __builtin_amdgcn_s_waitcnt(WAITCNT_VM0);
    __builtin_amdgcn_s_barrier();
  }

  // ---- epilogue ----
  const int r0 = (lane >> 4) * 4;
  const int cn = lane & 15;
  if (EPI == 0) {
#pragma unroll
    for (int i = 0; i < 8; ++i) {
      const int row = bm + wm * 128 + (i >> 2) * 64 + (i & 3) * 16 + r0;
#pragma unroll
      for (int j = 0; j < 4; ++j) {
        const int col = bn + wn * 64 + j * 16 + cn;
        const float bv = bias[col];
#pragma unroll
        for (int r = 0; r < 4; ++r) {
          float v = acc[i][j][r] + bv;
          v = 0.5f * v * (1.0f + erff(v * 0.7071067811865475f));   // exact GELU
          Co[(size_t)(row + r) * N + col] = (_Float16)v;
        }
      }
    }
  } else {
    const size_t zoff = (size_t)blockIdx.z * M;
#pragma unroll
    for (int i = 0; i < 8; ++i) {
      const int row = bm + wm * 128 + (i >> 2) * 64 + (i & 3) * 16 + r0;
#pragma unroll
      for (int j = 0; j < 4; ++j) {
        const int col = bn + wn * 64 + j * 16 + cn;
#pragma unroll
        for (int r = 0; r < 4; ++r)
          Co[(zoff + row + r) * N + col] = (_Float16)acc[i][j][r];
      }
    }
  }
}

// ---------------- finalize: out = x everywhere; selected rows += rw*(sum partials + b2) ----
__global__ __launch_bounds__(256) void finalize(const float* __restrict__ x,
                                                const _Float16* __restrict__ part,
                                                const float* __restrict__ bias,
                                                const int* __restrict__ selmap,
                                                const float* __restrict__ rw,
                                                float* __restrict__ out) {
  int row = blockIdx.x;                 // 0 .. B*S-1
  size_t base = (size_t)row * D_DIM;
  int sel = selmap[row];
  int c = threadIdx.x * 8;
  float4 o0 = *(const float4*)(x + base + c);
  float4 o1 = *(const float4*)(x + base + c + 4);
  if (sel >= 0) {
    float wgt = rw[sel];
    float acc[8] = {0, 0, 0, 0, 0, 0, 0, 0};
#pragma unroll
    for (int kz = 0; kz < NSPLIT; ++kz) {
      half8 p = *(const half8*)(part + ((size_t)kz * M_ROWS + sel) * D_DIM + c);
#pragma unroll
      for (int j = 0; j < 8; ++j) acc[j] += (float)p[j];
    }
    float4 b0 = *(const float4*)(bias + c);
    float4 b1 = *(const float4*)(bias + c + 4);
    o0.x += wgt * (acc[0] + b0.x);
    o0.y += wgt * (acc[1] + b0.y);
    o0.z += wgt * (acc[2] + b0.z);
    o0.w += wgt * (acc[3] + b0.w);
    o1.x += wgt * (acc[4] + b1.x);
    o1.y += wgt * (acc[5] + b1.y);
    o1.z += wgt * (acc[6] + b1.z);
    o1.w += wgt * (acc[7] + b1.w);
  }
  *(float4*)(out + base + c)     = o0;
  *(float4*)(out + base + c + 4) = o1;
}

// ---------------- launch ----------------
extern "C" void kernel_launch(void* const* d_in, const int* in_sizes, int n_in,
                              void* d_out, int out_size, void* d_ws, size_t ws_size,
                              hipStream_t stream) {
  const float* x  = (const float*)d_in[0];
  const float* Wr = (const float*)d_in[1];
  const float* br = (const float*)d_in[2];
  const float* W1 = (const float*)d_in[3];
  const float* b1 = (const float*)d_in[4];
  const float* W2 = (const float*)d_in[5];
  const float* b2 = (const float*)d_in[6];
  float* out = (float*)d_out;

  if (ws_size < WS_NEEDED) return;   // fail loudly (poisoned out) rather than corrupt

  char* ws = (char*)d_ws;
  float*     logits = (float*)(ws + OFF_LOGITS);
  int*       selmap = (int*)(ws + OFF_SELMAP);     // overlays logits
  int*       tokens = (int*)(ws + OFF_TOK);
  float*     rw     = (float*)(ws + OFF_RW);
  _Float16*  fx     = (_Float16*)(ws + OFF_FX);
  _Float16*  W1T    = (_Float16*)(ws + OFF_W1T);
  _Float16*  W2T    = (_Float16*)(ws + OFF_W2T);
  _Float16*  h      = (_Float16*)(ws + OFF_H);
  _Float16*  part   = (_Float16*)(ws + OFF_PART);  // overlays W1T (dead after gemm1)

  // weights: [K][N] f32 -> [N][K] f16
  transpose_cvt<<<dim3(DFF_DIM / 64, D_DIM / 64), 256, 0, stream>>>(W1, W1T, D_DIM, DFF_DIM);
  transpose_cvt<<<dim3(D_DIM / 64, DFF_DIM / 64), 256, 0, stream>>>(W2, W2T, DFF_DIM, D_DIM);

  router_logits<<<(B_DIM * S_DIM) / 4, 256, 0, stream>>>(x, Wr, br, logits);
  topk_select<<<B_DIM, 256, 0, stream>>>(logits, selmap, tokens, rw);
  gather_cvt<<<M_ROWS, 256, 0, stream>>>(x, tokens, fx);

  // h = gelu(fx @ W1 + b1)         grid 32x8 = 256 blocks (1/CU)
  gemm256<0><<<dim3(DFF_DIM / 256, M_ROWS / 256, 1), 512, 0, stream>>>(
      fx, W1T, b1, h, M_ROWS, DFF_DIM, D_DIM, D_DIM);
  // partials[kz] = h @ W2 (K-chunk kz)   grid 8x8x4 = 256 blocks
  gemm256<2><<<dim3(D_DIM / 256, M_ROWS / 256, NSPLIT), 512, 0, stream>>>(
      h, W2T, nullptr, part, M_ROWS, D_DIM, DFF_DIM, DFF_DIM / NSPLIT);
  // out = x; selected rows += rw * (sum partials + b2)
  finalize<<<B_DIM * S_DIM, 256, 0, stream>>>(x, part, b2, selmap, rw, out);
}